// Round 8
// baseline (96.635 us; speedup 1.0000x reference)
//
#include <hip/hip_runtime.h>

// Fused: out[b, c*9+d] = sum_hw fcn[b,c,hw] * kern[c*9+d, hw], row-L2-normalized.
// B=4096, C=128, D=9, HW=64, all fp32. One kernel; out written once.
//
// Latency-bound fix (R3..R7 all ~35us at 8 waves/CU): target 16 waves/CU.
// Needs VGPR<=128 (m69: 128-VGPR -> 16 waves/CU). Register diet:
//  - 512 thr = 64 groups x 8 lanes, NCH=2 -> keep[2][9]=18 regs
//  - d-loop split 5+4: kern regs <=40 per phase (fcn rows re-read per phase,
//    L1/L2-hot; +16 loads/thread is cheap vs 32 regs)
//  - no prefetch copies (TLP hides latency), 32-bit float4 indices
//  - sched_barrier(0) between phases: no cross-phase load hoisting (reg pressure)
// Reduce8 = 3 DPP adds (R7-proven: quad_perm xor1/xor2 + row_half_mirror).
// grid = 512 blocks x 8 waves = 16 waves/CU, grid-limited.

constexpr int B_TOT = 4096;
constexpr int C_CH  = 128;
constexpr int D_EMB = 9;
constexpr int THREADS = 512;
constexpr int RB  = 8;    // rows per block (= lanes per group)

__device__ __forceinline__ float reduce8_hw(float p) {
    // sum over the 8-lane group, VALU-only DPP
    p += __int_as_float(__builtin_amdgcn_mov_dpp(__float_as_int(p), 0xB1,  0xf, 0xf, true)); // xor1
    p += __int_as_float(__builtin_amdgcn_mov_dpp(__float_as_int(p), 0x4E,  0xf, 0xf, true)); // xor2
    p += __int_as_float(__builtin_amdgcn_mov_dpp(__float_as_int(p), 0x141, 0xf, 0xf, true)); // xor4 (row_half_mirror)
    return p;
}

__device__ __forceinline__ float dot8(const float4& a0, const float4& a1,
                                      const float4& b0, const float4& b1) {
    float t;
    t = a0.x * b0.x;
    t = fmaf(a0.y, b0.y, t);
    t = fmaf(a0.z, b0.z, t);
    t = fmaf(a0.w, b0.w, t);
    t = fmaf(a1.x, b1.x, t);
    t = fmaf(a1.y, b1.y, t);
    t = fmaf(a1.z, b1.z, t);
    t = fmaf(a1.w, b1.w, t);
    return t;
}

// One (channel, d-range) phase: load kern regs for ND d's, sweep 8 rows.
template<int D0, int ND>
__device__ __forceinline__ void phase(unsigned c, int l, unsigned b0,
                                      const float4* __restrict__ f4,
                                      const float4* __restrict__ kern4,
                                      float keep[D_EMB]) {
    float4 k0[ND], k1[ND];
#pragma unroll
    for (int d = 0; d < ND; ++d) {
        const unsigned kb = (c * D_EMB + (unsigned)(D0 + d)) * 16u;
        k0[d] = kern4[kb + l];
        k1[d] = kern4[kb + 8u + l];
    }
#pragma unroll
    for (int r = 0; r < RB; ++r) {
        const unsigned fb = ((b0 + (unsigned)r) * C_CH + c) * 16u;
        const float4 a0 = f4[fb + l];
        const float4 a1 = f4[fb + 8u + l];
#pragma unroll
        for (int d = 0; d < ND; ++d) {
            float t = dot8(a0, a1, k0[d], k1[d]);
            t = reduce8_hw(t);
            if (l == r) keep[D0 + d] = t;
        }
    }
}

__global__ __launch_bounds__(THREADS, 4)
void esenc_fused(const float* __restrict__ fcn,
                 const float* __restrict__ kern,
                 float* __restrict__ out) {
    __shared__ float red[8 * RB];   // 8 waves x 8 rows
    __shared__ float invn[RB];

    const int tid = threadIdx.x;
    const int l   = tid & 7;        // hw-slice lane, later row id
    const int g   = tid >> 3;       // group 0..63 (channel low bits)
    const int w   = tid >> 6;       // wave 0..7
    const unsigned b0 = blockIdx.x * RB;

    const float4* kern4 = (const float4*)kern;
    const float4* f4    = (const float4*)fcn;

    float keepA[D_EMB], keepB[D_EMB];

    phase<0, 5>((unsigned)g, l, b0, f4, kern4, keepA);
    __builtin_amdgcn_sched_barrier(0);
    phase<5, 4>((unsigned)g, l, b0, f4, kern4, keepA);
    __builtin_amdgcn_sched_barrier(0);
    phase<0, 5>((unsigned)(64 + g), l, b0, f4, kern4, keepB);
    __builtin_amdgcn_sched_barrier(0);
    phase<5, 4>((unsigned)(64 + g), l, b0, f4, kern4, keepB);

    // row-norm: per-thread sumsq (row l, channels g and 64+g)
    float s = 0.0f;
#pragma unroll
    for (int d = 0; d < D_EMB; ++d) {
        s = fmaf(keepA[d], keepA[d], s);
        s = fmaf(keepB[d], keepB[d], s);
    }
    s += __shfl_xor(s, 8,  64);   // reduce over the wave's 8 groups
    s += __shfl_xor(s, 16, 64);
    s += __shfl_xor(s, 32, 64);
    if ((tid & 63) < 8) red[w * RB + l] = s;
    __syncthreads();
    if (tid < RB) {
        float t = 0.0f;
#pragma unroll
        for (int j = 0; j < 8; ++j) t += red[j * RB + tid];
        invn[tid] = 1.0f / sqrtf(t + 1e-10f);
    }
    __syncthreads();
    const float inv = invn[l];

    // lane l owns row b0+l: channels g and 64+g, 9 floats each
    float* opA = out + (size_t)(b0 + l) * (C_CH * D_EMB) + g * D_EMB;
    float* opB = opA + 64 * D_EMB;
#pragma unroll
    for (int d = 0; d < D_EMB; ++d) {
        opA[d] = keepA[d] * inv;
        opB[d] = keepB[d] * inv;
    }
}

extern "C" void kernel_launch(void* const* d_in, const int* in_sizes, int n_in,
                              void* d_out, int out_size, void* d_ws, size_t ws_size,
                              hipStream_t stream) {
    const float* fcn  = (const float*)d_in[0];   // [4096,128,8,8] f32
    const float* kern = (const float*)d_in[1];   // [1,1152,8,8]  f32
    float* out = (float*)d_out;                  // [4096,1152]   f32

    dim3 grid(B_TOT / RB), block(THREADS);       // 512 blocks x 512 thr
    hipLaunchKernelGGL(esenc_fused, grid, block, 0, stream, fcn, kern, out);
}

// Round 9
// 52.463 us; speedup vs baseline: 1.8420x; 1.8420x over previous
//
#include <hip/hip_runtime.h>

// Fused: out[b, c*9+d] = sum_hw fcn[b,c,hw] * kern[c*9+d, hw], row-L2-normalized.
// B=4096, C=128, D=9, HW=64, all fp32. One kernel; out written once.
//
// 16-waves/CU attempt, corrected bound: on this toolchain __launch_bounds__'s
// 2nd arg acts as MIN BLOCKS/CU (empirical: (512,4)->64 VGPR [R5,R8],
// (512,2)->128 [R6], (256,2)->no cap hit [R7]). So (512,2) = 128-VGPR cap.
// Register diet so ~100 VGPR natural fits the cap (R6 failed at ~150):
//  - 512 thr = 64 groups x 8 lanes, NCH=2 -> keep 2x9 = 18 regs
//  - d-loop split 5+4: kern regs <=40 per phase (fcn rows re-read per phase;
//    16 KB/wave working set is L1-hot on the second phase)
//  - no prefetch copies (TLP hides latency), 32-bit float4 indices
//  - sched_barrier(0) between phases: no cross-phase load hoisting
// Reduce8 = 3 DPP adds (quad_perm xor1/xor2 + row_half_mirror), zero DS ops.
// grid = 512 blocks x 8 waves = 16 waves/CU. Spill tripwire: WRITE_SIZE 18.5MB.

constexpr int B_TOT = 4096;
constexpr int C_CH  = 128;
constexpr int D_EMB = 9;
constexpr int THREADS = 512;
constexpr int RB  = 8;    // rows per block (= lanes per group)

__device__ __forceinline__ float reduce8_hw(float p) {
    // sum over the 8-lane group, VALU-only DPP
    p += __int_as_float(__builtin_amdgcn_mov_dpp(__float_as_int(p), 0xB1,  0xf, 0xf, true)); // xor1
    p += __int_as_float(__builtin_amdgcn_mov_dpp(__float_as_int(p), 0x4E,  0xf, 0xf, true)); // xor2
    p += __int_as_float(__builtin_amdgcn_mov_dpp(__float_as_int(p), 0x141, 0xf, 0xf, true)); // xor4 (row_half_mirror)
    return p;
}

__device__ __forceinline__ float dot8(const float4& a0, const float4& a1,
                                      const float4& b0, const float4& b1) {
    float t;
    t = a0.x * b0.x;
    t = fmaf(a0.y, b0.y, t);
    t = fmaf(a0.z, b0.z, t);
    t = fmaf(a0.w, b0.w, t);
    t = fmaf(a1.x, b1.x, t);
    t = fmaf(a1.y, b1.y, t);
    t = fmaf(a1.z, b1.z, t);
    t = fmaf(a1.w, b1.w, t);
    return t;
}

// One (channel, d-range) phase: load kern regs for ND d's, sweep 8 rows.
template<int D0, int ND>
__device__ __forceinline__ void phase(unsigned c, int l, unsigned b0,
                                      const float4* __restrict__ f4,
                                      const float4* __restrict__ kern4,
                                      float keep[D_EMB]) {
    float4 k0[ND], k1[ND];
#pragma unroll
    for (int d = 0; d < ND; ++d) {
        const unsigned kb = (c * D_EMB + (unsigned)(D0 + d)) * 16u;
        k0[d] = kern4[kb + l];
        k1[d] = kern4[kb + 8u + l];
    }
#pragma unroll
    for (int r = 0; r < RB; ++r) {
        const unsigned fb = ((b0 + (unsigned)r) * C_CH + c) * 16u;
        const float4 a0 = f4[fb + l];
        const float4 a1 = f4[fb + 8u + l];
#pragma unroll
        for (int d = 0; d < ND; ++d) {
            float t = dot8(a0, a1, k0[d], k1[d]);
            t = reduce8_hw(t);
            if (l == r) keep[D0 + d] = t;
        }
    }
}

__global__ __launch_bounds__(THREADS, 2)
void esenc_fused(const float* __restrict__ fcn,
                 const float* __restrict__ kern,
                 float* __restrict__ out) {
    __shared__ float red[8 * RB];   // 8 waves x 8 rows
    __shared__ float invn[RB];

    const int tid = threadIdx.x;
    const int l   = tid & 7;        // hw-slice lane, later row id
    const int g   = tid >> 3;       // group 0..63 (channel low bits)
    const int w   = tid >> 6;       // wave 0..7
    const unsigned b0 = blockIdx.x * RB;

    const float4* kern4 = (const float4*)kern;
    const float4* f4    = (const float4*)fcn;

    float keepA[D_EMB], keepB[D_EMB];

    phase<0, 5>((unsigned)g, l, b0, f4, kern4, keepA);
    __builtin_amdgcn_sched_barrier(0);
    phase<5, 4>((unsigned)g, l, b0, f4, kern4, keepA);
    __builtin_amdgcn_sched_barrier(0);
    phase<0, 5>((unsigned)(64 + g), l, b0, f4, kern4, keepB);
    __builtin_amdgcn_sched_barrier(0);
    phase<5, 4>((unsigned)(64 + g), l, b0, f4, kern4, keepB);

    // row-norm: per-thread sumsq (row l, channels g and 64+g)
    float s = 0.0f;
#pragma unroll
    for (int d = 0; d < D_EMB; ++d) {
        s = fmaf(keepA[d], keepA[d], s);
        s = fmaf(keepB[d], keepB[d], s);
    }
    s += __shfl_xor(s, 8,  64);   // reduce over the wave's 8 groups
    s += __shfl_xor(s, 16, 64);
    s += __shfl_xor(s, 32, 64);
    if ((tid & 63) < 8) red[w * RB + l] = s;
    __syncthreads();
    if (tid < RB) {
        float t = 0.0f;
#pragma unroll
        for (int j = 0; j < 8; ++j) t += red[j * RB + tid];
        invn[tid] = 1.0f / sqrtf(t + 1e-10f);
    }
    __syncthreads();
    const float inv = invn[l];

    // lane l owns row b0+l: channels g and 64+g, 9 floats each
    float* opA = out + (size_t)(b0 + l) * (C_CH * D_EMB) + g * D_EMB;
    float* opB = opA + 64 * D_EMB;
#pragma unroll
    for (int d = 0; d < D_EMB; ++d) {
        opA[d] = keepA[d] * inv;
        opB[d] = keepB[d] * inv;
    }
}

extern "C" void kernel_launch(void* const* d_in, const int* in_sizes, int n_in,
                              void* d_out, int out_size, void* d_ws, size_t ws_size,
                              hipStream_t stream) {
    const float* fcn  = (const float*)d_in[0];   // [4096,128,8,8] f32
    const float* kern = (const float*)d_in[1];   // [1,1152,8,8]  f32
    float* out = (float*)d_out;                  // [4096,1152]   f32

    dim3 grid(B_TOT / RB), block(THREADS);       // 512 blocks x 512 thr
    hipLaunchKernelGGL(esenc_fused, grid, block, 0, stream, fcn, kern, out);
}